// Round 1
// 920.018 us; speedup vs baseline: 1.3374x; 1.3374x over previous
//
#include <hip/hip_runtime.h>
#include <math.h>

#define T 256
#define E 256
#define H 1024
#define I_DIM 256
#define CAP 256      // max tokens per expert (worst case = T)
#define NPASS 16     // CAP / 16

// ---------------- K1: logits = x @ gate_w^T, zero out, zero cnt ----------------
__global__ __launch_bounds__(256) void k1_logits(
    const float* __restrict__ x, const float* __restrict__ gw,
    float* __restrict__ logits, int* __restrict__ cnt, float* __restrict__ out)
{
    const int t = blockIdx.x, j = threadIdx.x;
    __shared__ __align__(16) float xs[H];
#pragma unroll
    for (int k = 0; k < 4; ++k) xs[k * 256 + j] = x[t * H + k * 256 + j];
#pragma unroll
    for (int k = 0; k < 4; ++k) out[t * H + k * 256 + j] = 0.f;
    if (t == 0) cnt[j] = 0;
    __syncthreads();
    const float4* w4 = (const float4*)(gw + (size_t)j * H);
    const float4* x4 = (const float4*)xs;
    float acc = 0.f;
#pragma unroll 8
    for (int h = 0; h < H / 4; ++h) {
        float4 w = w4[h];
        float4 v = x4[h];
        acc = fmaf(w.x, v.x, acc);
        acc = fmaf(w.y, v.y, acc);
        acc = fmaf(w.z, v.z, acc);
        acc = fmaf(w.w, v.w, acc);
    }
    logits[t * E + j] = acc;
}

// ---------------- K2: routing, one wave per token ----------------
__global__ __launch_bounds__(64) void k2_route(
    const float* __restrict__ logits, const float* __restrict__ e_bias,
    int* __restrict__ cnt, int* __restrict__ tok, float* __restrict__ wt)
{
    const int t = blockIdx.x;
    const int lane = threadIdx.x;   // 0..63, covers experts lane*4 .. lane*4+3

    float s[4], sc[4];
#pragma unroll
    for (int q = 0; q < 4; ++q) {
        int e = lane * 4 + q;
        float l = logits[t * E + e];
        float sig = 1.f / (1.f + expf(-l));
        s[q] = sig;                 // raw score (for weights)
        sc[q] = sig + e_bias[e];    // corrected score (for selection)
    }

    // local top-2 of 4
    float m01 = fmaxf(sc[0], sc[1]), n01 = fminf(sc[0], sc[1]);
    float m23 = fmaxf(sc[2], sc[3]), n23 = fminf(sc[2], sc[3]);
    float a1 = fmaxf(m01, m23);
    float a2 = fmaxf(fminf(m01, m23), fmaxf(n01, n23));
    // merge across the 8 lanes of this group (lanes g*8..g*8+7)
#pragma unroll
    for (int off = 1; off < 8; off <<= 1) {
        float b1 = __shfl_xor(a1, off);
        float b2 = __shfl_xor(a2, off);
        float na1 = fmaxf(a1, b1);
        float na2 = fmaxf(fminf(a1, b1), fmaxf(a2, b2));
        a1 = na1; a2 = na2;
    }
    float gs = a1 + a2;   // group score = sum of top-2

    __shared__ float gsc[8];
    if ((lane & 7) == 0) gsc[lane >> 3] = gs;
    __syncthreads();

    // top-4 groups of 8, lowest-index wins ties (matches lax.top_k)
    float lg[8];
#pragma unroll
    for (int g = 0; g < 8; ++g) lg[g] = gsc[g];
    unsigned gmask = 0;
#pragma unroll
    for (int k = 0; k < 4; ++k) {
        float best = -__builtin_inff(); int bi = 0;
#pragma unroll
        for (int g = 0; g < 8; ++g) {
            bool take = !((gmask >> g) & 1u) && (lg[g] > best);
            if (take) { best = lg[g]; bi = g; }
        }
        gmask |= 1u << bi;
    }

    bool gon = (gmask >> (lane >> 3)) & 1u;
    float masked[4];
#pragma unroll
    for (int q = 0; q < 4; ++q) masked[q] = gon ? sc[q] : -__builtin_inff();

    // iterative top-8 over 256 via wave argmax (tie -> lower index)
    int sel[8]; float selw[8]; float wsum = 0.f;
#pragma unroll
    for (int k = 0; k < 8; ++k) {
        float v = masked[0]; int qi = 0;
#pragma unroll
        for (int q = 1; q < 4; ++q) { if (masked[q] > v) { v = masked[q]; qi = q; } }
        int idx = lane * 4 + qi;
#pragma unroll
        for (int off = 1; off < 64; off <<= 1) {
            float ov = __shfl_xor(v, off);
            int   oi = __shfl_xor(idx, off);
            if (ov > v || (ov == v && oi < idx)) { v = ov; idx = oi; }
        }
        // idx is wave-uniform now
        float rawv = s[idx & 3];            // uniform selector
        rawv = __shfl(rawv, idx >> 2);      // broadcast from owning lane
        sel[k] = idx; selw[k] = rawv; wsum += rawv;
        if ((idx >> 2) == lane) masked[idx & 3] = -__builtin_inff();
    }
    float scale = 2.5f / (wsum + 1e-20f);

#pragma unroll
    for (int k = 0; k < 8; ++k) {
        if (lane == k) {
            int e = sel[k];
            int pos = atomicAdd(&cnt[e], 1);
            tok[e * CAP + pos] = t;
            wt[e * CAP + pos] = selw[k] * scale;
        }
    }
}

// ---------------- K3: unified expert passes ----------------
// Blocks 0..15: shared expert, token tile b (16 tokens), weight 1.0.
// Blocks 16.. : routed expert passes (e = (b-16)&255, pass p = (b-16)>>8).
// Both paths stream weights with 32-deep load batches (8 KB/wave in flight)
// so the 900-cycle HBM latency is covered by other waves' FMA work.
__global__ __launch_bounds__(256) void k3_experts(
    const float* __restrict__ x,
    const float* __restrict__ w_gate, const float* __restrict__ w_up,
    const float* __restrict__ w_down,
    const float* __restrict__ swg, const float* __restrict__ swu,
    const float* __restrict__ swd,
    const int* __restrict__ cnt, const int* __restrict__ tok,
    const float* __restrict__ wt, float* __restrict__ out)
{
    const int b = blockIdx.x;
    const int j = threadIdx.x;

    __shared__ __align__(16) float smem[16 * 256];  // x tiles, then activations
    __shared__ int   stok[16];
    __shared__ float swt_s[16];

    const float *wg, *wu, *wd;
    int nn;

    if (b < 16) {
        // shared expert: token tile b, all 16 tokens valid, weight 1
        if (j < 16) { stok[j] = b * 16 + j; swt_s[j] = 1.f; }
        wg = swg; wu = swu; wd = swd;
        nn = 16;
    } else {
        const int rb = b - 16;
        const int e = rb & 255;
        const int p = rb >> 8;
        const int n = cnt[e];
        const int base = p * 16;
        if (base >= n) return;
        nn = min(16, n - base);
        if (j < 16) {
            int tg = base + j;
            bool valid = tg < n;
            stok[j] = valid ? tok[e * CAP + tg] : tok[e * CAP + base];
            swt_s[j] = valid ? wt[e * CAP + tg] : 0.f;
        }
        wg = w_gate + (size_t)e * H * I_DIM;
        wu = w_up   + (size_t)e * H * I_DIM;
        wd = w_down + (size_t)e * I_DIM * H;
    }

    // ---- gate/up: thread j owns intermediate column j ----
    float h1[16], h3[16];
#pragma unroll
    for (int t2 = 0; t2 < 16; ++t2) { h1[t2] = 0.f; h3[t2] = 0.f; }

    for (int h0 = 0; h0 < H; h0 += 256) {
        __syncthreads();   // previous tile fully consumed (also covers stok/swt_s)
#pragma unroll
        for (int t2 = 0; t2 < 16; ++t2)
            smem[t2 * 256 + j] = x[(size_t)stok[t2] * H + h0 + j];
        __syncthreads();
#pragma unroll 1
        for (int hh = 0; hh < 256; hh += 16) {
            // batch 32 weight loads (16 gate + 16 up) -> 8 KB per wave in flight
            float wa[16], wb[16];
#pragma unroll
            for (int u = 0; u < 16; ++u)
                wa[u] = wg[(size_t)(h0 + hh + u) * I_DIM + j];
#pragma unroll
            for (int u = 0; u < 16; ++u)
                wb[u] = wu[(size_t)(h0 + hh + u) * I_DIM + j];
#pragma unroll
            for (int t2 = 0; t2 < 16; ++t2) {
                float xv[16];
                *(float4*)&xv[0]  = *(const float4*)&smem[t2 * 256 + hh];
                *(float4*)&xv[4]  = *(const float4*)&smem[t2 * 256 + hh + 4];
                *(float4*)&xv[8]  = *(const float4*)&smem[t2 * 256 + hh + 8];
                *(float4*)&xv[12] = *(const float4*)&smem[t2 * 256 + hh + 12];
                // ascending-h accumulation: identical rounding to baseline
#pragma unroll
                for (int u = 0; u < 16; ++u)
                    h1[t2] = fmaf(xv[u], wa[u], h1[t2]);
#pragma unroll
                for (int u = 0; u < 16; ++u)
                    h3[t2] = fmaf(xv[u], wb[u], h3[t2]);
            }
        }
    }
    __syncthreads();
    // silu(h1)*h3 -> smem as activations [16][256]
#pragma unroll
    for (int t2 = 0; t2 < 16; ++t2) {
        float v1 = h1[t2];
        float act = v1 / (1.f + __expf(-v1)) * h3[t2];
        smem[t2 * 256 + j] = act;
    }
    __syncthreads();
    // ---- down projection + weighted atomic accumulate ----
    for (int hblk = 0; hblk < 4; ++hblk) {
        float acc[16];
#pragma unroll
        for (int t2 = 0; t2 < 16; ++t2) acc[t2] = 0.f;
#pragma unroll 1
        for (int i = 0; i < I_DIM; i += 16) {
            float wv[16];
#pragma unroll
            for (int u = 0; u < 16; ++u)
                wv[u] = wd[(size_t)(i + u) * H + hblk * 256 + j];
#pragma unroll
            for (int t2 = 0; t2 < 16; ++t2) {
                float av[16];
                *(float4*)&av[0]  = *(const float4*)&smem[t2 * 256 + i];
                *(float4*)&av[4]  = *(const float4*)&smem[t2 * 256 + i + 4];
                *(float4*)&av[8]  = *(const float4*)&smem[t2 * 256 + i + 8];
                *(float4*)&av[12] = *(const float4*)&smem[t2 * 256 + i + 12];
                // ascending-i accumulation: identical rounding to baseline
#pragma unroll
                for (int u = 0; u < 16; ++u)
                    acc[t2] = fmaf(av[u], wv[u], acc[t2]);
            }
        }
#pragma unroll
        for (int t2 = 0; t2 < 16; ++t2) {
            if (t2 < nn)
                atomicAdd(&out[(size_t)stok[t2] * H + hblk * 256 + j],
                          swt_s[t2] * acc[t2]);
        }
    }
}

extern "C" void kernel_launch(void* const* d_in, const int* in_sizes, int n_in,
                              void* d_out, int out_size, void* d_ws, size_t ws_size,
                              hipStream_t stream) {
    const float* x      = (const float*)d_in[0];  // [1,1,T,H]
    const float* gate_w = (const float*)d_in[1];  // [E,H]
    const float* e_bias = (const float*)d_in[2];  // [E]
    const float* w_gate = (const float*)d_in[3];  // [E,H,I]
    const float* w_up   = (const float*)d_in[4];  // [E,H,I]
    const float* w_down = (const float*)d_in[5];  // [E,I,H]
    const float* swg    = (const float*)d_in[6];  // [H,I]
    const float* swu    = (const float*)d_in[7];  // [H,I]
    const float* swd    = (const float*)d_in[8];  // [I,H]
    float* out = (float*)d_out;

    float* wsf = (float*)d_ws;
    float* logits = wsf;                         // 65536 floats
    int*   cnt    = (int*)(wsf + 65536);         // 256 ints
    int*   tok    = (int*)(wsf + 65792);         // E*CAP ints
    float* wt     = wsf + 65792 + E * CAP;       // E*CAP floats

    k1_logits<<<T, 256, 0, stream>>>(x, gate_w, logits, cnt, out);
    k2_route<<<T, 64, 0, stream>>>(logits, e_bias, cnt, tok, wt);
    k3_experts<<<16 + E * NPASS, 256, 0, stream>>>(
        x, w_gate, w_up, w_down, swg, swu, swd, cnt, tok, wt, out);
}